// Round 18
// baseline (5735.304 us; speedup 1.0000x reference)
//
#include <hip/hip_runtime.h>
#include <hip/hip_bf16.h>
#include <math.h>

namespace {

constexpr int T = 1024;      // sequence length
constexpr int D = 768;       // model dim
constexpr int FF = 3072;     // ffn dim
constexpr int H = 12;        // heads
constexpr int HD = 64;       // head dim
constexpr int L = 12;        // layers
constexpr float SCALE = 0.125f;                 // 1/sqrt(64), exact power of 2
constexpr float MNEG = -1.0e30f;                // finite mask value (merge math)

typedef __attribute__((ext_vector_type(8))) short short8;
typedef __attribute__((ext_vector_type(4))) float floatx4;

__device__ inline unsigned short f2bf(float f) {
    __hip_bfloat16 h = __float2bfloat16(f);   // RNE
    return *reinterpret_cast<unsigned short*>(&h);
}
__device__ inline float bf2f(unsigned short u) {
    union { unsigned int i; float f; } c;
    c.i = (unsigned int)u << 16;
    return c.f;
}
// async global->LDS, 16B/lane; LDS dest = wave-uniform base + lane*16
__device__ inline void gld16(const void* g, void* l) {
    __builtin_amdgcn_global_load_lds(
        (const __attribute__((address_space(1))) void*)g,
        (__attribute__((address_space(3))) void*)l, 16, 0, 0);
}

// ---------------- counter init (graph-replay safe) ----------------
__global__ void zero_cnt(unsigned int* __restrict__ cnt, int n) {
    int i = blockIdx.x * blockDim.x + threadIdx.x;
    if (i < n) cnt[i] = 0u;
}

// ---------------- embedding: h0 = wte[ids] + wpe ----------------
__global__ void embed_kernel(const int* __restrict__ ids,
                             const float* __restrict__ wte,
                             const float* __restrict__ wpe,
                             float* __restrict__ h) {
    int i = blockIdx.x * blockDim.x + threadIdx.x;
    if (i >= T * D) return;
    int t = i / D, d = i % D;
    h[i] = wte[(long)ids[t] * D + d] + wpe[i];
}

// ---------------- layernorm (fp32 in, bf16 out), one row per block ----------------
__global__ __launch_bounds__(256)
void ln_kernel(const float* __restrict__ x, const float* __restrict__ g,
               const float* __restrict__ b, unsigned short* __restrict__ out) {
    int row = blockIdx.x, tid = threadIdx.x;
    const float* xr = x + (long)row * D;
    float v0 = xr[tid], v1 = xr[tid + 256], v2 = xr[tid + 512];
    __shared__ float red[4];
    __shared__ float share;
    float s = v0 + v1 + v2;
#pragma unroll
    for (int o = 32; o; o >>= 1) s += __shfl_down(s, o, 64);
    if ((tid & 63) == 0) red[tid >> 6] = s;
    __syncthreads();
    if (tid == 0) share = (red[0] + red[1] + red[2] + red[3]) * (1.0f / D);
    __syncthreads();
    float mu = share;
    float d0 = v0 - mu, d1 = v1 - mu, d2 = v2 - mu;
    float q = d0 * d0 + d1 * d1 + d2 * d2;
#pragma unroll
    for (int o = 32; o; o >>= 1) q += __shfl_down(q, o, 64);
    __syncthreads();
    if ((tid & 63) == 0) red[tid >> 6] = q;
    __syncthreads();
    if (tid == 0) share = rsqrtf((red[0] + red[1] + red[2] + red[3]) * (1.0f / D) + 1e-5f);
    __syncthreads();
    float rs = share;
    unsigned short* orow = out + (long)row * D;
    orow[tid]       = f2bf(d0 * rs * g[tid]       + b[tid]);
    orow[tid + 256] = f2bf(d1 * rs * g[tid + 256] + b[tid + 256]);
    orow[tid + 512] = f2bf(d2 * rs * g[tid + 512] + b[tid + 512]);
}

// ---------------- batched weight transpose+convert: WT[z][n][k] = bf16(W[z][k][n]) ----------------
__global__ __launch_bounds__(256)
void wconvert_b(const float* __restrict__ W, unsigned short* __restrict__ WT,
                int K, int N) {
    const int zl = blockIdx.z;
    W  += (long)zl * K * N;
    WT += (long)zl * N * K;
    __shared__ float t[32][33];
    const int n0 = blockIdx.x * 32, k0 = blockIdx.y * 32;
    const int tx = threadIdx.x, ty = threadIdx.y;
#pragma unroll
    for (int i = 0; i < 4; i++)
        t[ty * 4 + i][tx] = W[(long)(k0 + ty * 4 + i) * N + n0 + tx];
    __syncthreads();
#pragma unroll
    for (int i = 0; i < 4; i++)
        WT[(long)(n0 + ty * 4 + i) * K + k0 + tx] = f2bf(t[tx][ty * 4 + i]);
}

// ---------------- GEMM core: 128x64 tile, BK=64, 4 waves, per-wave 32x64 (2x4 frags) ----------------
#define GEMM_CORE(KLEN)                                                                 \
    floatx4 acc[2][4] = {};                                                             \
    gld16(ApA,      &As[0][ablk][0][0][0]);                                             \
    gld16(ApA + 32, &As[0][ablk][1][0][0]);                                             \
    gld16(ApB,      &As[0][ablk + 4][0][0][0]);                                         \
    gld16(ApB + 32, &As[0][ablk + 4][1][0][0]);                                         \
    gld16(Bp,       &Bs[0][ablk][0][0][0]);                                             \
    gld16(Bp + 32,  &Bs[0][ablk][1][0][0]);                                             \
    __syncthreads();                                                                    \
    const int nsteps = (KLEN) >> 6;                                                     \
    for (int s = 0; s < nsteps; s++) {                                                  \
        const int buf = s & 1;                                                          \
        const int nb = buf ^ 1;                                                         \
        if (s + 1 < nsteps) {                                                           \
            const long ko = (long)(s + 1) * 64;                                         \
            gld16(ApA + ko,      &As[nb][ablk][0][0][0]);                               \
            gld16(ApA + ko + 32, &As[nb][ablk][1][0][0]);                               \
            gld16(ApB + ko,      &As[nb][ablk + 4][0][0][0]);                           \
            gld16(ApB + ko + 32, &As[nb][ablk + 4][1][0][0]);                           \
            gld16(Bp + ko,       &Bs[nb][ablk][0][0][0]);                               \
            gld16(Bp + ko + 32,  &Bs[nb][ablk][1][0][0]);                               \
        }                                                                               \
        _Pragma("unroll")                                                               \
        for (int ks = 0; ks < 2; ks++) {                                                \
            short8 af[2], bfr[4];                                                       \
            _Pragma("unroll")                                                           \
            for (int mi = 0; mi < 2; mi++)                                              \
                af[mi] = *(const short8*)&As[buf][w * 2 + mi][ks][lane][0];             \
            _Pragma("unroll")                                                           \
            for (int ni = 0; ni < 4; ni++)                                              \
                bfr[ni] = *(const short8*)&Bs[buf][ni][ks][lane][0];                    \
            _Pragma("unroll")                                                           \
            for (int mi = 0; mi < 2; mi++)                                              \
                _Pragma("unroll")                                                       \
                for (int ni = 0; ni < 4; ni++)                                          \
                    acc[mi][ni] = __builtin_amdgcn_mfma_f32_16x16x32_bf16(              \
                        af[mi], bfr[ni], acc[mi][ni], 0, 0, 0);                         \
        }                                                                               \
        __syncthreads();                                                                \
    }

#define GEMM_PRELUDE(KOFF)                                                              \
    const int tid = threadIdx.x;                                                        \
    const int w = tid >> 6, lane = tid & 63;                                            \
    const int ablk = tid >> 6;                                                          \
    const int sl = tid & 63;                                                            \
    const int row0 = blockIdx.y * 128, col0 = blockIdx.x * 64;                          \
    __shared__ unsigned short As[2][8][2][64][8];                                       \
    __shared__ unsigned short Bs[2][4][2][64][8];                                       \
    const unsigned short* ApA = A + (long)(row0 + ablk * 16 + (sl & 15)) * K + (KOFF) + (sl >> 4) * 8; \
    const unsigned short* ApB = ApA + 64L * K;                                          \
    const unsigned short* Bp  = BT + (long)(col0 + ablk * 16 + (sl & 15)) * K + (KOFF) + (sl >> 4) * 8;

// ---------------- bf16 MFMA GEMM, fused epilogue (no split-K) ----------------
// flags: 1=bias, 4=gelu, 16=prescale cols<D by SCALE. grid (N/64, T/128)
__global__ __launch_bounds__(256)
void gemm_fused(const unsigned short* __restrict__ A, const unsigned short* __restrict__ BT,
                const float* __restrict__ bias, unsigned short* __restrict__ Cb,
                int N, int K, int flags) {
    GEMM_PRELUDE(0)
    GEMM_CORE(K)
#pragma unroll
    for (int mi = 0; mi < 2; mi++) {
        int rg = row0 + (w * 2 + mi) * 16 + (lane >> 4) * 4;
#pragma unroll
        for (int ni = 0; ni < 4; ni++) {
            int cg = col0 + ni * 16 + (lane & 15);
            float bv = (flags & 1) ? bias[cg] : 0.f;
            float bscale = ((flags & 16) && cg < D) ? SCALE : 1.0f;
#pragma unroll
            for (int r = 0; r < 4; r++) {
                float v = acc[mi][ni][r] + bv;
                if (flags & 4) {
                    float zz = 0.7978845608028654f * (v + 0.044715f * v * v * v);
                    v = v / (1.0f + __expf(-2.0f * zz));
                }
                Cb[(long)(rg + r) * N + cg] = f2bf(v * bscale);
            }
        }
    }
}

// ---------------- bf16 MFMA GEMM, split-K=4 + SEMAPHORE-FUSED reduce+residual+LN ----------------
// grid (D/64=12, T/128=8, 4). After writing partials, last-arriving block per
// row-tile (counter==47) performs reduce + residual + LN for its 128 rows
// (2 threads/row, halves merged by shfl_xor(1)). Output math is a pure function
// of completed partials -> deterministic regardless of arrival order.
__global__ __launch_bounds__(256)
void gemm_ln(const unsigned short* __restrict__ A, const unsigned short* __restrict__ BT,
             float* __restrict__ part, const float* __restrict__ bias,
             const float* __restrict__ resid,
             const float* __restrict__ g, const float* __restrict__ b,
             float* __restrict__ Cres, unsigned short* __restrict__ Cln,
             unsigned int* __restrict__ cnt, int K) {
    const int z = blockIdx.z;
    const int Kc = K / 4;
    GEMM_PRELUDE(z * Kc)
    GEMM_CORE(Kc)
    float* dst = part + (long)z * T * D;
#pragma unroll
    for (int mi = 0; mi < 2; mi++) {
        int rg = row0 + (w * 2 + mi) * 16 + (lane >> 4) * 4;
#pragma unroll
        for (int ni = 0; ni < 4; ni++) {
            int cg = col0 + ni * 16 + (lane & 15);
#pragma unroll
            for (int r = 0; r < 4; r++)
                dst[(long)(rg + r) * D + cg] = acc[mi][ni][r];
        }
    }
    // ---- semaphore: release partials, last block per row-tile does the LN ----
    __threadfence();                    // device-scope release (cross-XCD)
    __shared__ unsigned int oldv;
    if (tid == 0) oldv = atomicAdd(&cnt[blockIdx.y], 1u);
    __syncthreads();
    if (oldv != 47u) return;            // 12 x-blocks * 4 z-blocks - 1
    __threadfence();                    // acquire

    const int r2 = tid >> 1;            // row 0..127
    const int hf = tid & 1;             // half 0/1 (384 cols each)
    const long rb2 = (long)(row0 + r2) * D + hf * 384;
    const int cb0 = hf * 384;
    // pass 1: v = bias + resid + sum_z part[z]; write Cres; accumulate row-sum
    float s = 0.f;
    for (int c = 0; c < 384; c += 4) {
        float4 v = *(const float4*)(bias + cb0 + c);
        float4 rv = *(const float4*)(resid + rb2 + c);
        v.x += rv.x; v.y += rv.y; v.z += rv.z; v.w += rv.w;
#pragma unroll
        for (int zz = 0; zz < 4; zz++) {
            float4 p = *(const float4*)(part + (long)zz * T * D + rb2 + c);
            v.x += p.x; v.y += p.y; v.z += p.z; v.w += p.w;
        }
        *(float4*)(Cres + rb2 + c) = v;
        s += v.x + v.y + v.z + v.w;
    }
    s += __shfl_xor(s, 1);
    float mu = s * (1.0f / D);
    // pass 2: variance from Cres
    float q = 0.f;
    for (int c = 0; c < 384; c += 4) {
        float4 v = *(const float4*)(Cres + rb2 + c);
        float d0 = v.x - mu, d1 = v.y - mu, d2 = v.z - mu, d3 = v.w - mu;
        q += d0 * d0 + d1 * d1 + d2 * d2 + d3 * d3;
    }
    q += __shfl_xor(q, 1);
    float rs = rsqrtf(q * (1.0f / D) + 1e-5f);
    // pass 3: bf16 LN output
    for (int c = 0; c < 384; c += 4) {
        float4 v = *(const float4*)(Cres + rb2 + c);
        float4 gv = *(const float4*)(g + cb0 + c);
        float4 bv = *(const float4*)(b + cb0 + c);
        unsigned int p0 = (unsigned)f2bf((v.x - mu) * rs * gv.x + bv.x) |
                          ((unsigned)f2bf((v.y - mu) * rs * gv.y + bv.y) << 16);
        unsigned int p1 = (unsigned)f2bf((v.z - mu) * rs * gv.z + bv.z) |
                          ((unsigned)f2bf((v.w - mu) * rs * gv.w + bv.w) << 16);
        *(uint2*)(Cln + rb2 + c) = make_uint2(p0, p1);
    }
}

// ---------------- probe body (device): softmax row S2 or T-1 for head h ----------------
__device__ void probe_body(const unsigned short* __restrict__ qkvb,
                           const int* __restrict__ Sp, const int* __restrict__ Sa1p,
                           const int* __restrict__ S2p,
                           float* __restrict__ out, int layer, int which, int h) {
    const int s = *Sp, sa1 = *Sa1p, s2 = *S2p;
    const int row = which ? (T - 1) : s2;
    const int tid = threadIdx.x;
    __shared__ float qrow[64];
    __shared__ float prob[T];
    __shared__ float red[4];
    __shared__ float bshare;
    if (tid < 64) qrow[tid] = bf2f(qkvb[(long)row * (3 * D) + h * HD + tid]);
    __syncthreads();
    float mloc = -INFINITY;
    for (int j = tid; j <= row; j += 256) {
        const unsigned short* krow = qkvb + (long)j * (3 * D) + D + h * HD;
        float acc = 0;
#pragma unroll
        for (int d = 0; d < 64; d += 8) {
            short8 kv = *(const short8*)(krow + d);
#pragma unroll
            for (int e = 0; e < 8; e++)
                acc += qrow[d + e] * bf2f((unsigned short)kv[e]);
        }
        prob[j] = acc;   // Q pre-scaled by SCALE (exact pow2)
        mloc = fmaxf(mloc, acc);
    }
#pragma unroll
    for (int o = 32; o; o >>= 1) mloc = fmaxf(mloc, __shfl_down(mloc, o, 64));
    if ((tid & 63) == 0) red[tid >> 6] = mloc;
    __syncthreads();
    if (tid == 0) bshare = fmaxf(fmaxf(red[0], red[1]), fmaxf(red[2], red[3]));
    __syncthreads();
    float m = bshare;
    float ssum = 0;
    for (int j = tid; j <= row; j += 256) {
        float e = expf(prob[j] - m);
        prob[j] = e;
        ssum += e;
    }
#pragma unroll
    for (int o = 32; o; o >>= 1) ssum += __shfl_down(ssum, o, 64);
    __syncthreads();
    if ((tid & 63) == 0) red[tid >> 6] = ssum;
    __syncthreads();
    if (tid == 0) bshare = red[0] + red[1] + red[2] + red[3];
    __syncthreads();
    float inv = 1.0f / bshare;
    if (tid == 0) {
        if (which == 0) {
            out[0 * (L * H) + layer * H + h] = prob[s] * inv;
            out[1 * (L * H) + layer * H + h] = prob[sa1] * inv;
        } else {
            out[2 * (L * H) + layer * H + h] = prob[s2] * inv;
            out[3 * (L * H) + layer * H + h] = prob[s2] * inv;
        }
    }
}

// ---------------- standalone probe (last layer) ----------------
__global__ __launch_bounds__(256)
void probe_kernel(const unsigned short* __restrict__ qkvb,
                  const int* __restrict__ Sp, const int* __restrict__ Sa1p,
                  const int* __restrict__ S2p,
                  float* __restrict__ out, int layer) {
    probe_body(qkvb, Sp, Sa1p, S2p, out, layer, blockIdx.x, blockIdx.y);
}

// ---------------- MFMA flash attention (32 q-rows/block, wave-pair KV split) + probes ----------------
// T14 async-STAGE; setprio around MFMA clusters (kept from R17, neutral/harmless).
__global__ __launch_bounds__(256)
void flash_probe(const unsigned short* __restrict__ qkvb, unsigned short* __restrict__ ctxb,
                 const int* __restrict__ Sp, const int* __restrict__ Sa1p,
                 const int* __restrict__ S2p, float* __restrict__ out, int layer) {
    const int h = blockIdx.y;
    if (blockIdx.x >= T / 32) {   // probe blocks (fill idle CUs; block-uniform branch)
        probe_body(qkvb, Sp, Sa1p, S2p, out, layer, blockIdx.x - T / 32, h);
        return;
    }
    const int q0 = blockIdx.x * 32;
    const int tid = threadIdx.x;
    const int w = tid >> 6;
    const int pair = w >> 1;      // 0,1: q-row group
    const int sub = w & 1;        // 0,1: KV half of each tile
    const int l = tid & 63;
    const int lm = l & 15;
    const int g = l >> 4;

    __shared__ unsigned short Kl[64][72];
    __shared__ unsigned short Vt[64][80];
    __shared__ unsigned short Pl[4][16][72];

    const int qw = q0 + pair * 16;

    short8 qf[2];
    {
        const unsigned short* qp = qkvb + (long)(qw + lm) * (3 * D) + h * HD + g * 8;
        qf[0] = *(const short8*)(qp);
        qf[1] = *(const short8*)(qp + 32);
    }

    const int d8 = (tid & 7) * 8;
    const int kp = (tid >> 3) * 2;
    const unsigned short* kbase = qkvb + (long)kp * (3 * D) + D + h * HD + d8;

    float m = MNEG, lsum = 0.f;
    floatx4 o[4] = {};
    const int nt = blockIdx.x / 2 + 1;   // covers KV up to q0+31

    // prologue: load tile 0 into registers
    short8 rk0, rk1, rv0, rv1;
    {
        const unsigned short* kr0 = kbase;
        rk0 = *(const short8*)kr0;
        rk1 = *(const short8*)(kr0 + 3 * D);
        rv0 = *(const short8*)(kr0 + D);
        rv1 = *(const short8*)(kr0 + D + 3 * D);
    }

    for (int t = 0; t < nt; t++) {
        __syncthreads();   // previous tile's LDS reads complete
        *(short8*)&Kl[kp][d8]     = rk0;
        *(short8*)&Kl[kp + 1][d8] = rk1;
#pragma unroll
        for (int j = 0; j < 8; j++) {
            unsigned int pk = (unsigned)(unsigned short)rv0[j] |
                              ((unsigned)(unsigned short)rv1[j] << 16);
            *(unsigned int*)&Vt[d8 + j][kp] = pk;
        }
        if (t + 1 < nt) {   // issue tile t+1 loads; latency hides under compute
            const unsigned short* kr0 = kbase + (long)(t + 1) * 64 * (3 * D);
            rk0 = *(const short8*)kr0;
            rk1 = *(const short8*)(kr0 + 3 * D);
            rv0 = *(const short8*)(kr0 + D);
            rv1 = *(const short8*)(kr0 + D + 3 * D);
        }
        __syncthreads();   // LDS ready

        const int c0 = t * 64;
        floatx4 st[2] = {};
        __builtin_amdgcn_s_setprio(1);
#pragma unroll
        for (int ks = 0; ks < 2; ks++)
#pragma unroll
            for (int m2 = 0; m2 < 2; m2++) {
                short8 af = *(const short8*)&Kl[(sub * 2 + m2) * 16 + lm][ks * 32 + g * 8];
                st[m2] = __builtin_amdgcn_mfma_f32_16x16x32_bf16(af, qf[ks], st[m2], 0, 0, 0);
            }
        __builtin_amdgcn_s_setprio(0);

        const int qg = qw + lm;
        const int cb = c0 + sub * 32;
        if (cb + 31 > qw) {
#pragma unroll
            for (int m2 = 0; m2 < 2; m2++)
#pragma unroll
                for (int r = 0; r < 4; r++)
                    if (cb + m2 * 16 + g * 4 + r > qg) st[m2][r] = MNEG;
        }
        float tmax = fmaxf(fmaxf(fmaxf(st[0][0], st[0][1]), fmaxf(st[0][2], st[0][3])),
                           fmaxf(fmaxf(st[1][0], st[1][1]), fmaxf(st[1][2], st[1][3])));
        tmax = fmaxf(tmax, __shfl_xor(tmax, 16));
        tmax = fmaxf(tmax, __shfl_xor(tmax, 32));
        float mn = fmaxf(m, tmax);
        float alpha = __expf(m - mn);
        float psum = 0.f;
        unsigned short pb[8];
#pragma unroll
        for (int m2 = 0; m2 < 2; m2++)
#pragma unroll
            for (int r = 0; r < 4; r++) {
                float p = __expf(st[m2][r] - mn);
                psum += p;
                pb[m2 * 4 + r] = f2bf(p);
            }
        lsum = lsum * alpha + psum;
        m = mn;
#pragma unroll
        for (int m2 = 0; m2 < 2; m2++) {
            unsigned int p0 = (unsigned)pb[m2 * 4 + 0] | ((unsigned)pb[m2 * 4 + 1] << 16);
            unsigned int p1 = (unsigned)pb[m2 * 4 + 2] | ((unsigned)pb[m2 * 4 + 3] << 16);
            *(unsigned int*)&Pl[w][lm][(sub * 2 + m2) * 16 + g * 4]     = p0;
            *(unsigned int*)&Pl[w][lm][(sub * 2 + m2) * 16 + g * 4 + 2] = p1;
        }
        float ar0 = __shfl(alpha, g * 4 + 0), ar1 = __shfl(alpha, g * 4 + 1);
        float ar2 = __shfl(alpha, g * 4 + 2), ar3 = __shfl(alpha, g * 4 + 3);
#pragma unroll
        for (int fd = 0; fd < 4; fd++) {
            o[fd][0] *= ar0; o[fd][1] *= ar1; o[fd][2] *= ar2; o[fd][3] *= ar3;
        }
        {
            short8 pa = *(const short8*)&Pl[w][lm][sub * 32 + g * 8];
            __builtin_amdgcn_s_setprio(1);
#pragma unroll
            for (int fd = 0; fd < 4; fd++) {
                short8 vb = *(const short8*)&Vt[fd * 16 + lm][sub * 32 + g * 8];
                o[fd] = __builtin_amdgcn_mfma_f32_16x16x32_bf16(pa, vb, o[fd], 0, 0, 0);
            }
            __builtin_amdgcn_s_setprio(0);
        }
    }
    float l2 = lsum + __shfl_xor(lsum, 16);
    float l4 = l2 + __shfl_xor(l2, 32);

    // ---- end-of-block merge of the two KV halves (alias Om/Ml onto Kl) ----
    float* Om = (float*)&Kl[0][0];                    // [2][16][68] = 8704 B
    float2* Mlb = (float2*)((char*)Om + 2 * 16 * 68 * 4);  // [2][16]  = 256 B
    __syncthreads();   // all waves done reading Kl/Vt
    if (sub == 1) {
        if (g == 0) Mlb[pair * 16 + lm] = make_float2(m, l4);
#pragma unroll
        for (int fd = 0; fd < 4; fd++)
#pragma unroll
            for (int r = 0; r < 4; r++)
                Om[(pair * 16 + g * 4 + r) * 68 + fd * 16 + lm] = o[fd][r];
    }
    __syncthreads();
    if (sub == 0) {
        float2 oth = Mlb[pair * 16 + lm];
        float M = fmaxf(m, oth.x);
        float e0 = __expf(m - M), e1 = __expf(oth.x - M);
        float inv = 1.0f / (l4 * e0 + oth.y * e1);
        float a0 = e0 * inv, a1 = e1 * inv;
#pragma unroll
        for (int fd = 0; fd < 4; fd++) {
            unsigned short* cp = ctxb + (long)(qw + g * 4) * D + h * HD + fd * 16 + lm;
#pragma unroll
            for (int r = 0; r < 4; r++) {
                float w0r = __shfl(a0, g * 4 + r);
                float w1r = __shfl(a1, g * 4 + r);
                float val = o[fd][r] * w0r +
                            Om[(pair * 16 + g * 4 + r) * 68 + fd * 16 + lm] * w1r;
                cp[(long)r * D] = f2bf(val);
            }
        }
    }
}

}  // namespace

extern "C" void kernel_launch(void* const* d_in, const int* in_sizes, int n_in,
                              void* d_out, int out_size, void* d_ws, size_t ws_size,
                              hipStream_t stream) {
    const int*   ids    = (const int*)  d_in[0];
    const float* wte    = (const float*)d_in[2];
    const float* wpe    = (const float*)d_in[3];
    const float* ln1_g  = (const float*)d_in[4];
    const float* ln1_b  = (const float*)d_in[5];
    const float* W_qkv  = (const float*)d_in[6];
    const float* b_qkv  = (const float*)d_in[7];
    const float* W_o    = (const float*)d_in[8];
    const float* b_o    = (const float*)d_in[9];
    const float* ln2_g  = (const float*)d_in[10];
    const float* ln2_b  = (const float*)d_in[11];
    const float* W_fc   = (const float*)d_in[12];
    const float* b_fc   = (const float*)d_in[13];
    const float* W_proj = (const float*)d_in[14];
    const float* b_proj = (const float*)d_in[15];
    const int*   Sp     = (const int*)  d_in[16];
    const int*   Sa1p   = (const int*)  d_in[17];
    const int*   S2p    = (const int*)  d_in[18];
    float* out = (float*)d_out;

    float* ws   = (float*)d_ws;
    float* h    = ws;                      // T*D fp32 residual
    float* h2   = h   + (long)T * D;       // T*D fp32
    float* part = h2  + (long)T * D;       // 4*T*D fp32 split partials
    unsigned short* xl   = (unsigned short*)(part + 4L * T * D);   // T*D bf16
    unsigned short* qkvb = xl   + (long)T * D;                     // T*3D bf16 (Q pre-scaled)
    unsigned short* ctxb = qkvb + (long)T * 3 * D;                 // T*D bf16
    unsigned short* fb   = ctxb + (long)T * D;                     // T*FF bf16
    unsigned short* wt_qkv  = fb      + (long)T * FF;
    unsigned short* wt_o    = wt_qkv  + (long)L * 3 * D * D;
    unsigned short* wt_fc   = wt_o    + (long)L * D * D;
    unsigned short* wt_proj = wt_fc   + (long)L * D * FF;
    unsigned int*   cnt     = (unsigned int*)(wt_proj + (long)L * FF * D);  // 22*8 counters

    const int NCNT = 2 * L * 8;   // 2 fused-LN gemms per layer, 8 row-tiles

    // upfront: counters + embedding + ALL weight conversions (parallel)
    zero_cnt<<<(NCNT + 255) / 256, 256, 0, stream>>>(cnt, NCNT);
    embed_kernel<<<(T * D + 255) / 256, 256, 0, stream>>>(ids, wte, wpe, h);
    wconvert_b<<<dim3(3 * D / 32, D / 32, L), dim3(32, 8), 0, stream>>>(W_qkv, wt_qkv, D, 3 * D);
    wconvert_b<<<dim3(D / 32, D / 32, L), dim3(32, 8), 0, stream>>>(W_o, wt_o, D, D);
    wconvert_b<<<dim3(FF / 32, D / 32, L), dim3(32, 8), 0, stream>>>(W_fc, wt_fc, D, FF);
    wconvert_b<<<dim3(D / 32, FF / 32, L), dim3(32, 8), 0, stream>>>(W_proj, wt_proj, FF, D);
    // layer-0 ln1 (subsequent LNs fused into gemm_ln epilogues)
    ln_kernel<<<T, 256, 0, stream>>>(h, ln1_g, ln1_b, xl);

    for (int l = 0; l < L; l++) {
        // qkvb = bf16(xl @ W_qkv + b_qkv), Q cols pre-scaled by SCALE
        gemm_fused<<<dim3(3 * D / 64, T / 128), 256, 0, stream>>>(
            xl, wt_qkv + (long)l * 3 * D * D, b_qkv + (long)l * 3 * D,
            qkvb, 3 * D, D, 1 | 16);

        if (l == L - 1) {   // last layer: only the probes are needed
            probe_kernel<<<dim3(2, H), 256, 0, stream>>>(qkvb, Sp, Sa1p, S2p, out, l);
            break;
        }

        // ctx = causal-softmax(QK^T) @ V  + probe blocks fused into same launch
        flash_probe<<<dim3(T / 32 + 2, H), 256, 0, stream>>>(
            qkvb, ctxb, Sp, Sa1p, S2p, out, l);
        // h2 = h + ctx @ W_o + b_o ; xl = ln2(h2)   [fused semaphore epilogue]
        gemm_ln<<<dim3(D / 64, T / 128, 4), 256, 0, stream>>>(
            ctxb, wt_o + (long)l * D * D, part, b_o + (long)l * D, h,
            ln2_g + l * D, ln2_b + l * D, h2, xl, cnt + (l * 2 + 0) * 8, D);
        // f = gelu(xl @ W_fc + b_fc)  (bf16 out)
        gemm_fused<<<dim3(FF / 64, T / 128), 256, 0, stream>>>(
            xl, wt_fc + (long)l * D * FF, b_fc + (long)l * FF, fb, FF, D, 1 | 4);
        // h = h2 + f @ W_proj + b_proj ; xl = ln1_{l+1}(h)   [fused semaphore epilogue]
        gemm_ln<<<dim3(D / 64, T / 128, 4), 256, 0, stream>>>(
            fb, wt_proj + (long)l * D * FF, part, b_proj + (long)l * D, h2,
            ln1_g + (l + 1) * D, ln1_b + (l + 1) * D, h, xl, cnt + (l * 2 + 1) * 8, FF);
    }
}

// Round 19
// 1256.569 us; speedup vs baseline: 4.5643x; 4.5643x over previous
//
#include <hip/hip_runtime.h>
#include <hip/hip_bf16.h>
#include <math.h>

namespace {

constexpr int T = 1024;      // sequence length
constexpr int D = 768;       // model dim
constexpr int FF = 3072;     // ffn dim
constexpr int H = 12;        // heads
constexpr int HD = 64;       // head dim
constexpr int L = 12;        // layers
constexpr float SCALE = 0.125f;                 // 1/sqrt(64), exact power of 2
constexpr float MNEG = -1.0e30f;                // finite mask value (merge math)

typedef __attribute__((ext_vector_type(8))) short short8;
typedef __attribute__((ext_vector_type(4))) float floatx4;

__device__ inline unsigned short f2bf(float f) {
    __hip_bfloat16 h = __float2bfloat16(f);   // RNE
    return *reinterpret_cast<unsigned short*>(&h);
}
__device__ inline float bf2f(unsigned short u) {
    union { unsigned int i; float f; } c;
    c.i = (unsigned int)u << 16;
    return c.f;
}
// async global->LDS, 16B/lane; LDS dest = wave-uniform base + lane*16
__device__ inline void gld16(const void* g, void* l) {
    __builtin_amdgcn_global_load_lds(
        (const __attribute__((address_space(1))) void*)g,
        (__attribute__((address_space(3))) void*)l, 16, 0, 0);
}

// ---------------- embedding: h0 = wte[ids] + wpe ----------------
__global__ void embed_kernel(const int* __restrict__ ids,
                             const float* __restrict__ wte,
                             const float* __restrict__ wpe,
                             float* __restrict__ h) {
    int i = blockIdx.x * blockDim.x + threadIdx.x;
    if (i >= T * D) return;
    int t = i / D, d = i % D;
    h[i] = wte[(long)ids[t] * D + d] + wpe[i];
}

// ---------------- layernorm (fp32 in, bf16 out), one row per block ----------------
__global__ __launch_bounds__(256)
void ln_kernel(const float* __restrict__ x, const float* __restrict__ g,
               const float* __restrict__ b, unsigned short* __restrict__ out) {
    int row = blockIdx.x, tid = threadIdx.x;
    const float* xr = x + (long)row * D;
    float v0 = xr[tid], v1 = xr[tid + 256], v2 = xr[tid + 512];
    __shared__ float red[4];
    __shared__ float share;
    float s = v0 + v1 + v2;
#pragma unroll
    for (int o = 32; o; o >>= 1) s += __shfl_down(s, o, 64);
    if ((tid & 63) == 0) red[tid >> 6] = s;
    __syncthreads();
    if (tid == 0) share = (red[0] + red[1] + red[2] + red[3]) * (1.0f / D);
    __syncthreads();
    float mu = share;
    float d0 = v0 - mu, d1 = v1 - mu, d2 = v2 - mu;
    float q = d0 * d0 + d1 * d1 + d2 * d2;
#pragma unroll
    for (int o = 32; o; o >>= 1) q += __shfl_down(q, o, 64);
    __syncthreads();
    if ((tid & 63) == 0) red[tid >> 6] = q;
    __syncthreads();
    if (tid == 0) share = rsqrtf((red[0] + red[1] + red[2] + red[3]) * (1.0f / D) + 1e-5f);
    __syncthreads();
    float rs = share;
    unsigned short* orow = out + (long)row * D;
    orow[tid]       = f2bf(d0 * rs * g[tid]       + b[tid]);
    orow[tid + 256] = f2bf(d1 * rs * g[tid + 256] + b[tid + 256]);
    orow[tid + 512] = f2bf(d2 * rs * g[tid + 512] + b[tid + 512]);
}

// ---------------- batched weight transpose+convert: WT[z][n][k] = bf16(W[z][k][n]) ----------------
__global__ __launch_bounds__(256)
void wconvert_b(const float* __restrict__ W, unsigned short* __restrict__ WT,
                int K, int N) {
    const int zl = blockIdx.z;
    W  += (long)zl * K * N;
    WT += (long)zl * N * K;
    __shared__ float t[32][33];
    const int n0 = blockIdx.x * 32, k0 = blockIdx.y * 32;
    const int tx = threadIdx.x, ty = threadIdx.y;
#pragma unroll
    for (int i = 0; i < 4; i++)
        t[ty * 4 + i][tx] = W[(long)(k0 + ty * 4 + i) * N + n0 + tx];
    __syncthreads();
#pragma unroll
    for (int i = 0; i < 4; i++)
        WT[(long)(n0 + ty * 4 + i) * K + k0 + tx] = f2bf(t[tx][ty * 4 + i]);
}

// ---------------- GEMM core: 128x64 tile, BK=64, 4 waves, per-wave 32x64 (2x4 frags) ----------------
// Staging via async global_load_lds; accumulation order identical to BK=32 version.
#define GEMM_CORE(KLEN)                                                                 \
    floatx4 acc[2][4] = {};                                                             \
    gld16(ApA,      &As[0][ablk][0][0][0]);                                             \
    gld16(ApA + 32, &As[0][ablk][1][0][0]);                                             \
    gld16(ApB,      &As[0][ablk + 4][0][0][0]);                                         \
    gld16(ApB + 32, &As[0][ablk + 4][1][0][0]);                                         \
    gld16(Bp,       &Bs[0][ablk][0][0][0]);                                             \
    gld16(Bp + 32,  &Bs[0][ablk][1][0][0]);                                             \
    __syncthreads();                                                                    \
    const int nsteps = (KLEN) >> 6;                                                     \
    for (int s = 0; s < nsteps; s++) {                                                  \
        const int buf = s & 1;                                                          \
        const int nb = buf ^ 1;                                                         \
        if (s + 1 < nsteps) {                                                           \
            const long ko = (long)(s + 1) * 64;                                         \
            gld16(ApA + ko,      &As[nb][ablk][0][0][0]);                               \
            gld16(ApA + ko + 32, &As[nb][ablk][1][0][0]);                               \
            gld16(ApB + ko,      &As[nb][ablk + 4][0][0][0]);                           \
            gld16(ApB + ko + 32, &As[nb][ablk + 4][1][0][0]);                           \
            gld16(Bp + ko,       &Bs[nb][ablk][0][0][0]);                               \
            gld16(Bp + ko + 32,  &Bs[nb][ablk][1][0][0]);                               \
        }                                                                               \
        _Pragma("unroll")                                                               \
        for (int ks = 0; ks < 2; ks++) {                                                \
            short8 af[2], bfr[4];                                                       \
            _Pragma("unroll")                                                           \
            for (int mi = 0; mi < 2; mi++)                                              \
                af[mi] = *(const short8*)&As[buf][w * 2 + mi][ks][lane][0];             \
            _Pragma("unroll")                                                           \
            for (int ni = 0; ni < 4; ni++)                                              \
                bfr[ni] = *(const short8*)&Bs[buf][ni][ks][lane][0];                    \
            _Pragma("unroll")                                                           \
            for (int mi = 0; mi < 2; mi++)                                              \
                _Pragma("unroll")                                                       \
                for (int ni = 0; ni < 4; ni++)                                          \
                    acc[mi][ni] = __builtin_amdgcn_mfma_f32_16x16x32_bf16(              \
                        af[mi], bfr[ni], acc[mi][ni], 0, 0, 0);                         \
        }                                                                               \
        __syncthreads();                                                                \
    }

#define GEMM_PRELUDE(KOFF)                                                              \
    const int tid = threadIdx.x;                                                        \
    const int w = tid >> 6, lane = tid & 63;                                            \
    const int ablk = tid >> 6;                                                          \
    const int sl = tid & 63;                                                            \
    const int row0 = blockIdx.y * 128, col0 = blockIdx.x * 64;                          \
    __shared__ unsigned short As[2][8][2][64][8];                                       \
    __shared__ unsigned short Bs[2][4][2][64][8];                                       \
    const unsigned short* ApA = A + (long)(row0 + ablk * 16 + (sl & 15)) * K + (KOFF) + (sl >> 4) * 8; \
    const unsigned short* ApB = ApA + 64L * K;                                          \
    const unsigned short* Bp  = BT + (long)(col0 + ablk * 16 + (sl & 15)) * K + (KOFF) + (sl >> 4) * 8;

// ---------------- bf16 MFMA GEMM, fused epilogue (no split-K) ----------------
// flags: 1=bias, 4=gelu, 16=prescale cols<D by SCALE. grid (N/64, T/128)
__global__ __launch_bounds__(256)
void gemm_fused(const unsigned short* __restrict__ A, const unsigned short* __restrict__ BT,
                const float* __restrict__ bias, unsigned short* __restrict__ Cb,
                int N, int K, int flags) {
    GEMM_PRELUDE(0)
    GEMM_CORE(K)
#pragma unroll
    for (int mi = 0; mi < 2; mi++) {
        int rg = row0 + (w * 2 + mi) * 16 + (lane >> 4) * 4;
#pragma unroll
        for (int ni = 0; ni < 4; ni++) {
            int cg = col0 + ni * 16 + (lane & 15);
            float bv = (flags & 1) ? bias[cg] : 0.f;
            float bscale = ((flags & 16) && cg < D) ? SCALE : 1.0f;
#pragma unroll
            for (int r = 0; r < 4; r++) {
                float v = acc[mi][ni][r] + bv;
                if (flags & 4) {
                    float zz = 0.7978845608028654f * (v + 0.044715f * v * v * v);
                    v = v / (1.0f + __expf(-2.0f * zz));
                }
                Cb[(long)(rg + r) * N + cg] = f2bf(v * bscale);
            }
        }
    }
}

// ---------------- bf16 MFMA GEMM, split-K, fp32 partials. grid (N/64, T/128, splitK) ----------------
__global__ __launch_bounds__(256)
void gemm_bf16(const unsigned short* __restrict__ A, const unsigned short* __restrict__ BT,
               float* __restrict__ part, int N, int K, int splitK) {
    const int z = blockIdx.z;
    const int Kc = K / splitK;
    GEMM_PRELUDE(z * Kc)
    GEMM_CORE(Kc)
    float* dst = part + (long)z * T * N;
#pragma unroll
    for (int mi = 0; mi < 2; mi++) {
        int rg = row0 + (w * 2 + mi) * 16 + (lane >> 4) * 4;
#pragma unroll
        for (int ni = 0; ni < 4; ni++) {
            int cg = col0 + ni * 16 + (lane & 15);
#pragma unroll
            for (int r = 0; r < 4; r++)
                dst[(long)(rg + r) * N + cg] = acc[mi][ni][r];
        }
    }
}

// ---------------- split-K reduce + residual + LayerNorm fused (float4 vectorized) ----------------
// 256 threads/row; threads 0..191 each own 4 consecutive cols (float4 loads, uint2 bf16 store).
__global__ __launch_bounds__(256)
void reduce_ln(const float* __restrict__ part, const float* __restrict__ bias,
               const float* __restrict__ resid,
               const float* __restrict__ g, const float* __restrict__ b,
               float* __restrict__ Cres, unsigned short* __restrict__ Cln,
               int splitK) {
    const int row = blockIdx.x, tid = threadIdx.x;
    const long rb = (long)row * D;
    const int c4 = tid * 4;
    const bool act = (tid < 192);   // 192*4 = 768 = D
    float4 v = {0.f, 0.f, 0.f, 0.f};
    if (act) {
        v = *(const float4*)(bias + c4);
        float4 rv = *(const float4*)(resid + rb + c4);
        v.x += rv.x; v.y += rv.y; v.z += rv.z; v.w += rv.w;
        for (int z = 0; z < splitK; z++) {
            float4 p = *(const float4*)(part + (long)z * T * D + rb + c4);
            v.x += p.x; v.y += p.y; v.z += p.z; v.w += p.w;
        }
        *(float4*)(Cres + rb + c4) = v;
    }
    __shared__ float red[4];
    __shared__ float share;
    float s = v.x + v.y + v.z + v.w;
#pragma unroll
    for (int o = 32; o; o >>= 1) s += __shfl_down(s, o, 64);
    if ((tid & 63) == 0) red[tid >> 6] = s;
    __syncthreads();
    if (tid == 0) share = (red[0] + red[1] + red[2] + red[3]) * (1.0f / D);
    __syncthreads();
    float mu = share;
    float d0 = v.x - mu, d1 = v.y - mu, d2 = v.z - mu, d3 = v.w - mu;
    float q = act ? (d0 * d0 + d1 * d1 + d2 * d2 + d3 * d3) : 0.f;
#pragma unroll
    for (int o = 32; o; o >>= 1) q += __shfl_down(q, o, 64);
    __syncthreads();
    if ((tid & 63) == 0) red[tid >> 6] = q;
    __syncthreads();
    if (tid == 0) share = rsqrtf((red[0] + red[1] + red[2] + red[3]) * (1.0f / D) + 1e-5f);
    __syncthreads();
    float rs = share;
    if (act) {
        float4 gv = *(const float4*)(g + c4);
        float4 bv = *(const float4*)(b + c4);
        unsigned int p0 = (unsigned)f2bf(d0 * rs * gv.x + bv.x) |
                          ((unsigned)f2bf(d1 * rs * gv.y + bv.y) << 16);
        unsigned int p1 = (unsigned)f2bf(d2 * rs * gv.z + bv.z) |
                          ((unsigned)f2bf(d3 * rs * gv.w + bv.w) << 16);
        uint2 pk = make_uint2(p0, p1);
        *(uint2*)(Cln + rb + c4) = pk;
    }
}

// ---------------- probe body (device): softmax row S2 or T-1 for head h ----------------
__device__ void probe_body(const unsigned short* __restrict__ qkvb,
                           const int* __restrict__ Sp, const int* __restrict__ Sa1p,
                           const int* __restrict__ S2p,
                           float* __restrict__ out, int layer, int which, int h) {
    const int s = *Sp, sa1 = *Sa1p, s2 = *S2p;
    const int row = which ? (T - 1) : s2;
    const int tid = threadIdx.x;
    __shared__ float qrow[64];
    __shared__ float prob[T];
    __shared__ float red[4];
    __shared__ float bshare;
    if (tid < 64) qrow[tid] = bf2f(qkvb[(long)row * (3 * D) + h * HD + tid]);
    __syncthreads();
    float mloc = -INFINITY;
    for (int j = tid; j <= row; j += 256) {
        const unsigned short* krow = qkvb + (long)j * (3 * D) + D + h * HD;
        float acc = 0;
#pragma unroll
        for (int d = 0; d < 64; d += 8) {
            short8 kv = *(const short8*)(krow + d);
#pragma unroll
            for (int e = 0; e < 8; e++)
                acc += qrow[d + e] * bf2f((unsigned short)kv[e]);
        }
        prob[j] = acc;   // Q pre-scaled by SCALE (exact pow2)
        mloc = fmaxf(mloc, acc);
    }
#pragma unroll
    for (int o = 32; o; o >>= 1) mloc = fmaxf(mloc, __shfl_down(mloc, o, 64));
    if ((tid & 63) == 0) red[tid >> 6] = mloc;
    __syncthreads();
    if (tid == 0) bshare = fmaxf(fmaxf(red[0], red[1]), fmaxf(red[2], red[3]));
    __syncthreads();
    float m = bshare;
    float ssum = 0;
    for (int j = tid; j <= row; j += 256) {
        float e = expf(prob[j] - m);
        prob[j] = e;
        ssum += e;
    }
#pragma unroll
    for (int o = 32; o; o >>= 1) ssum += __shfl_down(ssum, o, 64);
    __syncthreads();
    if ((tid & 63) == 0) red[tid >> 6] = ssum;
    __syncthreads();
    if (tid == 0) bshare = red[0] + red[1] + red[2] + red[3];
    __syncthreads();
    float inv = 1.0f / bshare;
    if (tid == 0) {
        if (which == 0) {
            out[0 * (L * H) + layer * H + h] = prob[s] * inv;
            out[1 * (L * H) + layer * H + h] = prob[sa1] * inv;
        } else {
            out[2 * (L * H) + layer * H + h] = prob[s2] * inv;
            out[3 * (L * H) + layer * H + h] = prob[s2] * inv;
        }
    }
}

// ---------------- standalone probe (last layer) ----------------
__global__ __launch_bounds__(256)
void probe_kernel(const unsigned short* __restrict__ qkvb,
                  const int* __restrict__ Sp, const int* __restrict__ Sa1p,
                  const int* __restrict__ S2p,
                  float* __restrict__ out, int layer) {
    probe_body(qkvb, Sp, Sa1p, S2p, out, layer, blockIdx.x, blockIdx.y);
}

// ---------------- MFMA flash attention (32 q-rows/block, wave-pair KV split) + probes ----------------
// T14 async-STAGE + T5 setprio around MFMA clusters.
__global__ __launch_bounds__(256)
void flash_probe(const unsigned short* __restrict__ qkvb, unsigned short* __restrict__ ctxb,
                 const int* __restrict__ Sp, const int* __restrict__ Sa1p,
                 const int* __restrict__ S2p, float* __restrict__ out, int layer) {
    const int h = blockIdx.y;
    if (blockIdx.x >= T / 32) {   // probe blocks (fill idle CUs; block-uniform branch)
        probe_body(qkvb, Sp, Sa1p, S2p, out, layer, blockIdx.x - T / 32, h);
        return;
    }
    const int q0 = blockIdx.x * 32;
    const int tid = threadIdx.x;
    const int w = tid >> 6;
    const int pair = w >> 1;      // 0,1: q-row group
    const int sub = w & 1;        // 0,1: KV half of each tile
    const int l = tid & 63;
    const int lm = l & 15;
    const int g = l >> 4;

    __shared__ unsigned short Kl[64][72];
    __shared__ unsigned short Vt[64][80];
    __shared__ unsigned short Pl[4][16][72];

    const int qw = q0 + pair * 16;

    short8 qf[2];
    {
        const unsigned short* qp = qkvb + (long)(qw + lm) * (3 * D) + h * HD + g * 8;
        qf[0] = *(const short8*)(qp);
        qf[1] = *(const short8*)(qp + 32);
    }

    const int d8 = (tid & 7) * 8;
    const int kp = (tid >> 3) * 2;
    const unsigned short* kbase = qkvb + (long)kp * (3 * D) + D + h * HD + d8;

    float m = MNEG, lsum = 0.f;
    floatx4 o[4] = {};
    const int nt = blockIdx.x / 2 + 1;   // covers KV up to q0+31

    // prologue: load tile 0 into registers
    short8 rk0, rk1, rv0, rv1;
    {
        const unsigned short* kr0 = kbase;
        rk0 = *(const short8*)kr0;
        rk1 = *(const short8*)(kr0 + 3 * D);
        rv0 = *(const short8*)(kr0 + D);
        rv1 = *(const short8*)(kr0 + D + 3 * D);
    }

    for (int t = 0; t < nt; t++) {
        __syncthreads();   // previous tile's LDS reads complete
        // write staged registers (tile t) to LDS
        *(short8*)&Kl[kp][d8]     = rk0;
        *(short8*)&Kl[kp + 1][d8] = rk1;
#pragma unroll
        for (int j = 0; j < 8; j++) {
            unsigned int pk = (unsigned)(unsigned short)rv0[j] |
                              ((unsigned)(unsigned short)rv1[j] << 16);
            *(unsigned int*)&Vt[d8 + j][kp] = pk;
        }
        // issue tile t+1 loads now; latency spans the compute phase below
        if (t + 1 < nt) {
            const unsigned short* kr0 = kbase + (long)(t + 1) * 64 * (3 * D);
            rk0 = *(const short8*)kr0;
            rk1 = *(const short8*)(kr0 + 3 * D);
            rv0 = *(const short8*)(kr0 + D);
            rv1 = *(const short8*)(kr0 + D + 3 * D);
        }
        __syncthreads();   // LDS ready

        const int c0 = t * 64;
        // S^T for this wave's KV half: rows sub*32..sub*32+31 of the tile
        floatx4 st[2] = {};
        __builtin_amdgcn_s_setprio(1);
#pragma unroll
        for (int ks = 0; ks < 2; ks++)
#pragma unroll
            for (int m2 = 0; m2 < 2; m2++) {
                short8 af = *(const short8*)&Kl[(sub * 2 + m2) * 16 + lm][ks * 32 + g * 8];
                st[m2] = __builtin_amdgcn_mfma_f32_16x16x32_bf16(af, qf[ks], st[m2], 0, 0, 0);
            }
        __builtin_amdgcn_s_setprio(0);

        const int qg = qw + lm;
        const int cb = c0 + sub * 32;
        if (cb + 31 > qw) {   // tile half may cross the diagonal
#pragma unroll
            for (int m2 = 0; m2 < 2; m2++)
#pragma unroll
                for (int r = 0; r < 4; r++)
                    if (cb + m2 * 16 + g * 4 + r > qg) st[m2][r] = MNEG;
        }
        float tmax = fmaxf(fmaxf(fmaxf(st[0][0], st[0][1]), fmaxf(st[0][2], st[0][3])),
                           fmaxf(fmaxf(st[1][0], st[1][1]), fmaxf(st[1][2], st[1][3])));
        tmax = fmaxf(tmax, __shfl_xor(tmax, 16));
        tmax = fmaxf(tmax, __shfl_xor(tmax, 32));
        float mn = fmaxf(m, tmax);
        float alpha = __expf(m - mn);
        float psum = 0.f;
        unsigned short pb[8];
#pragma unroll
        for (int m2 = 0; m2 < 2; m2++)
#pragma unroll
            for (int r = 0; r < 4; r++) {
                float p = __expf(st[m2][r] - mn);
                psum += p;
                pb[m2 * 4 + r] = f2bf(p);
            }
        lsum = lsum * alpha + psum;
        m = mn;
        // P^T -> wave-private LDS slots for this wave's k-range [sub*32, sub*32+32)
#pragma unroll
        for (int m2 = 0; m2 < 2; m2++) {
            unsigned int p0 = (unsigned)pb[m2 * 4 + 0] | ((unsigned)pb[m2 * 4 + 1] << 16);
            unsigned int p1 = (unsigned)pb[m2 * 4 + 2] | ((unsigned)pb[m2 * 4 + 3] << 16);
            *(unsigned int*)&Pl[w][lm][(sub * 2 + m2) * 16 + g * 4]     = p0;
            *(unsigned int*)&Pl[w][lm][(sub * 2 + m2) * 16 + g * 4 + 2] = p1;
        }
        float ar0 = __shfl(alpha, g * 4 + 0), ar1 = __shfl(alpha, g * 4 + 1);
        float ar2 = __shfl(alpha, g * 4 + 2), ar3 = __shfl(alpha, g * 4 + 3);
#pragma unroll
        for (int fd = 0; fd < 4; fd++) {
            o[fd][0] *= ar0; o[fd][1] *= ar1; o[fd][2] *= ar2; o[fd][3] *= ar3;
        }
        // PV over this wave's KV half (ks = sub)
        {
            short8 pa = *(const short8*)&Pl[w][lm][sub * 32 + g * 8];
            __builtin_amdgcn_s_setprio(1);
#pragma unroll
            for (int fd = 0; fd < 4; fd++) {
                short8 vb = *(const short8*)&Vt[fd * 16 + lm][sub * 32 + g * 8];
                o[fd] = __builtin_amdgcn_mfma_f32_16x16x32_bf16(pa, vb, o[fd], 0, 0, 0);
            }
            __builtin_amdgcn_s_setprio(0);
        }
    }
    // per-wave half row-sum
    float l2 = lsum + __shfl_xor(lsum, 16);
    float l4 = l2 + __shfl_xor(l2, 32);

    // ---- end-of-block merge of the two KV halves (alias Om/Ml onto Kl) ----
    float* Om = (float*)&Kl[0][0];                    // [2][16][68] = 8704 B
    float2* Mlb = (float2*)((char*)Om + 2 * 16 * 68 * 4);  // [2][16]  = 256 B
    __syncthreads();   // all waves done reading Kl/Vt
    if (sub == 1) {
        if (g == 0) Mlb[pair * 16 + lm] = make_float2(m, l4);
#pragma unroll
        for (int fd = 0; fd < 4; fd++)
#pragma unroll
            for (int r = 0; r < 4; r++)
                Om[(pair * 16 + g * 4 + r) * 68 + fd * 16 + lm] = o[fd][r];
    }
    __syncthreads();
    if (sub == 0) {
        float2 oth = Mlb[pair * 16 + lm];
        float M = fmaxf(m, oth.x);
        float e0 = __expf(m - M), e1 = __expf(oth.x - M);
        float inv = 1.0f / (l4 * e0 + oth.y * e1);
        float a0 = e0 * inv, a1 = e1 * inv;
#pragma unroll
        for (int fd = 0; fd < 4; fd++) {
            unsigned short* cp = ctxb + (long)(qw + g * 4) * D + h * HD + fd * 16 + lm;
#pragma unroll
            for (int r = 0; r < 4; r++) {
                float w0r = __shfl(a0, g * 4 + r);
                float w1r = __shfl(a1, g * 4 + r);
                float val = o[fd][r] * w0r +
                            Om[(pair * 16 + g * 4 + r) * 68 + fd * 16 + lm] * w1r;
                cp[(long)r * D] = f2bf(val);
            }
        }
    }
}

}  // namespace

extern "C" void kernel_launch(void* const* d_in, const int* in_sizes, int n_in,
                              void* d_out, int out_size, void* d_ws, size_t ws_size,
                              hipStream_t stream) {
    const int*   ids    = (const int*)  d_in[0];
    const float* wte    = (const float*)d_in[2];
    const float* wpe    = (const float*)d_in[3];
    const float* ln1_g  = (const float*)d_in[4];
    const float* ln1_b  = (const float*)d_in[5];
    const float* W_qkv  = (const float*)d_in[6];
    const float* b_qkv  = (const float*)d_in[7];
    const float* W_o    = (const float*)d_in[8];
    const float* b_o    = (const float*)d_in[9];
    const float* ln2_g  = (const float*)d_in[10];
    const float* ln2_b  = (const float*)d_in[11];
    const float* W_fc   = (const float*)d_in[12];
    const float* b_fc   = (const float*)d_in[13];
    const float* W_proj = (const float*)d_in[14];
    const float* b_proj = (const float*)d_in[15];
    const int*   Sp     = (const int*)  d_in[16];
    const int*   Sa1p   = (const int*)  d_in[17];
    const int*   S2p    = (const int*)  d_in[18];
    float* out = (float*)d_out;

    float* ws   = (float*)d_ws;
    float* h    = ws;                      // T*D fp32 residual
    float* h2   = h   + (long)T * D;       // T*D fp32
    float* part = h2  + (long)T * D;       // 4*T*D fp32 split partials
    unsigned short* xl   = (unsigned short*)(part + 4L * T * D);   // T*D bf16
    unsigned short* qkvb = xl   + (long)T * D;                     // T*3D bf16 (Q pre-scaled)
    unsigned short* ctxb = qkvb + (long)T * 3 * D;                 // T*D bf16
    unsigned short* fb   = ctxb + (long)T * D;                     // T*FF bf16
    unsigned short* wt_qkv  = fb      + (long)T * FF;
    unsigned short* wt_o    = wt_qkv  + (long)L * 3 * D * D;
    unsigned short* wt_fc   = wt_o    + (long)L * D * D;
    unsigned short* wt_proj = wt_fc   + (long)L * D * FF;

    // upfront: embedding + ALL weight conversions (parallel, batched over layers)
    embed_kernel<<<(T * D + 255) / 256, 256, 0, stream>>>(ids, wte, wpe, h);
    wconvert_b<<<dim3(3 * D / 32, D / 32, L), dim3(32, 8), 0, stream>>>(W_qkv, wt_qkv, D, 3 * D);
    wconvert_b<<<dim3(D / 32, D / 32, L), dim3(32, 8), 0, stream>>>(W_o, wt_o, D, D);
    wconvert_b<<<dim3(FF / 32, D / 32, L), dim3(32, 8), 0, stream>>>(W_fc, wt_fc, D, FF);
    wconvert_b<<<dim3(D / 32, FF / 32, L), dim3(32, 8), 0, stream>>>(W_proj, wt_proj, FF, D);
    // layer-0 ln1 (subsequent LNs fused into reduce_ln)
    ln_kernel<<<T, 256, 0, stream>>>(h, ln1_g, ln1_b, xl);

    for (int l = 0; l < L; l++) {
        // qkvb = bf16(xl @ W_qkv + b_qkv), Q cols pre-scaled by SCALE
        gemm_fused<<<dim3(3 * D / 64, T / 128), 256, 0, stream>>>(
            xl, wt_qkv + (long)l * 3 * D * D, b_qkv + (long)l * 3 * D,
            qkvb, 3 * D, D, 1 | 16);

        if (l == L - 1) {   // last layer: only the probes are needed
            probe_kernel<<<dim3(2, H), 256, 0, stream>>>(qkvb, Sp, Sa1p, S2p, out, l);
            break;
        }

        // ctx = causal-softmax(QK^T) @ V  + probe blocks fused into same launch
        flash_probe<<<dim3(T / 32 + 2, H), 256, 0, stream>>>(
            qkvb, ctxb, Sp, Sa1p, S2p, out, l);
        // h2 = h + ctx @ W_o + b_o ; xl = ln2(h2)
        gemm_bf16<<<dim3(D / 64, T / 128, 4), 256, 0, stream>>>(
            ctxb, wt_o + (long)l * D * D, part, D, D, 4);
        reduce_ln<<<T, 256, 0, stream>>>(
            part, b_o + (long)l * D, h, ln2_g + l * D, ln2_b + l * D, h2, xl, 4);
        // f = gelu(xl @ W_fc + b_fc)  (bf16 out)
        gemm_fused<<<dim3(FF / 64, T / 128), 256, 0, stream>>>(
            xl, wt_fc + (long)l * D * FF, b_fc + (long)l * FF, fb, FF, D, 1 | 4);
        // h = h2 + f @ W_proj + b_proj ; xl = ln1_{l+1}(h)
        gemm_bf16<<<dim3(D / 64, T / 128, 4), 256, 0, stream>>>(
            fb, wt_proj + (long)l * D * FF, part, D, FF, 4);
        reduce_ln<<<T, 256, 0, stream>>>(
            part, b_proj + (long)l * D, h2, ln1_g + (l + 1) * D, ln1_b + (l + 1) * D, h, xl, 4);
    }
}